// Round 3
// baseline (1454.573 us; speedup 1.0000x reference)
//
#include <hip/hip_runtime.h>

// IM2HT Hough voting:
//   out[b,c,ht] = sum_{n: ht_idx[n]==ht} input_im[b,c,im_idx[n]] * weight[n]
// B*C = 128, HW = 16384, NHT = 184*180 = 33120, N = 1.5M votes.
//
// Pipeline:
//   1. k_zero         : zero bucket cursors + overflow counter
//   2. k_transpose_in : in[BC][HW] -> xT[HW][BC] (512 B per pixel row)
//   3. k_bucket       : multi-split votes into 552 coarse ht-ranges (60 bins each),
//                       per-block private chunks -> L2-mergeable writes,
//                       ~200K global atomics instead of 1.5M
//   4. k_accum2       : one block per range; LDS accumulator acc[60][128] (pad 129),
//                       unroll-8 pipelined gathers + ds_add_f32; writes out[ch][ht]
//                       directly (transpose fused)
//   5. k_overflow     : exact-correctness fallback (empty in practice)

#define HW   16384
#define BC   128
#define NHT  33120
#define RB   60            // ht bins per range
#define NB   552           // NHT / RB (exact)
#define CAPB 4096          // record capacity per bucket (mean 2717, +26 sigma)
#define VPB  4096          // votes per k_bucket block
#define OFL_CAP 8192
#define ST   129           // padded LDS stride for acc

__global__ void k_zero(int* __restrict__ gcur, int* __restrict__ ofl_cnt) {
  int i = blockIdx.x * blockDim.x + threadIdx.x;
  if (i < NB) gcur[i] = 0;
  if (i == NB) *ofl_cnt = 0;
}

// in [BC][HW] -> xT [HW][BC]
__global__ void k_transpose_in(const float* __restrict__ in, float* __restrict__ xT) {
  __shared__ float tile[32][33];
  int hw0 = blockIdx.x * 32, bc0 = blockIdx.y * 32;
  int tx = threadIdx.x, ty = threadIdx.y;
#pragma unroll
  for (int k = 0; k < 32; k += 8)
    tile[ty + k][tx] = in[(size_t)(bc0 + ty + k) * HW + hw0 + tx];  // coalesced on hw
  __syncthreads();
#pragma unroll
  for (int k = 0; k < 32; k += 8)
    xT[(size_t)(hw0 + ty + k) * BC + bc0 + tx] = tile[tx][ty + k];  // coalesced on bc
}

__global__ __launch_bounds__(256) void k_bucket(
    const int* __restrict__ im, const int* __restrict__ ht,
    const float* __restrict__ wt, int n,
    int* __restrict__ gcur, int2* __restrict__ bkt,
    int* __restrict__ ofl_cnt, int2* __restrict__ ofl) {
  __shared__ int cnt[NB];
  __shared__ int base[NB];
  int tid = threadIdx.x;
  int i0 = blockIdx.x * VPB;
  for (int b = tid; b < NB; b += 256) cnt[b] = 0;
  __syncthreads();
  int hv[16];
#pragma unroll
  for (int k = 0; k < 16; ++k) {
    int i = i0 + k * 256 + tid;
    hv[k] = (i < n) ? ht[i] : -1;
    if (i < n) atomicAdd(&cnt[hv[k] / RB], 1);
  }
  __syncthreads();
  for (int b = tid; b < NB; b += 256) {
    int c = cnt[b];
    base[b] = c ? atomicAdd(&gcur[b], c) : 0;  // reserve private chunk
    cnt[b] = 0;                                 // reuse as local cursor
  }
  __syncthreads();
#pragma unroll
  for (int k = 0; k < 16; ++k) {
    int i = i0 + k * 256 + tid;
    if (i < n) {
      int h = hv[k];
      int b = h / RB;
      int hl = h - b * RB;
      int pos = base[b] + atomicAdd(&cnt[b], 1);
      if (pos < CAPB) {
        bkt[(size_t)b * CAPB + pos] =
            make_int2((im[i] & 0x3FFF) | (hl << 14), __float_as_int(wt[i]));
      } else {
        int o = atomicAdd(ofl_cnt, 1);
        if (o < OFL_CAP)
          ofl[o] = make_int2((im[i] & 0x3FFF) | (h << 14), __float_as_int(wt[i]));
      }
    }
  }
}

// one block per ht-range; lane l owns channels l and l+64
__global__ __launch_bounds__(256) void k_accum2(
    const int2* __restrict__ bkt, const int* __restrict__ gcur,
    const float* __restrict__ xT, float* __restrict__ out) {
  __shared__ float acc[RB * ST];
  int tid = threadIdx.x;
  int r = blockIdx.x;
  for (int k = tid; k < RB * ST; k += 256) acc[k] = 0.f;
  __syncthreads();
  int n = gcur[r];
  if (n > CAPB) n = CAPB;
  const int2* s = bkt + (size_t)r * CAPB;
  int w = tid >> 6, lane = tid & 63;
  int i = w;
  // unroll-8 pipelined: 8 independent rec loads, 16 independent gathers, then LDS
  for (; i + 28 < n; i += 32) {
    int2 rv[8];
#pragma unroll
    for (int u = 0; u < 8; ++u) rv[u] = s[i + 4 * u];
    float xa[8], xb[8];
#pragma unroll
    for (int u = 0; u < 8; ++u) {
      int imp = (rv[u].x & 0x3FFF) << 7;
      xa[u] = xT[imp + lane];
      xb[u] = xT[imp + 64 + lane];
    }
#pragma unroll
    for (int u = 0; u < 8; ++u) {
      int hl = rv[u].x >> 14;
      float wgt = __int_as_float(rv[u].y);
      atomicAdd(&acc[hl * ST + lane], wgt * xa[u]);
      atomicAdd(&acc[hl * ST + 64 + lane], wgt * xb[u]);
    }
  }
  for (; i < n; i += 4) {
    int2 rv = s[i];
    int imp = (rv.x & 0x3FFF) << 7;
    int hl = rv.x >> 14;
    float wgt = __int_as_float(rv.y);
    atomicAdd(&acc[hl * ST + lane], wgt * xT[imp + lane]);
    atomicAdd(&acc[hl * ST + 64 + lane], wgt * xT[imp + 64 + lane]);
  }
  __syncthreads();
  int ht0 = r * RB;
  for (int k = tid; k < BC * RB; k += 256) {
    int ch = k / RB, j = k - ch * RB;
    out[(size_t)ch * NHT + ht0 + j] = acc[j * ST + ch];  // bank- & coalesce-friendly
  }
}

// exact-correctness fallback; *ofl_cnt == 0 in practice -> immediate exit
__global__ void k_overflow(const int* __restrict__ ofl_cnt, const int2* __restrict__ ofl,
                           const float* __restrict__ xT, float* __restrict__ out) {
  int cnt = *ofl_cnt;
  if (cnt > OFL_CAP) cnt = OFL_CAP;
  int c = threadIdx.x;  // 0..127 channel
  for (int v = blockIdx.x; v < cnt; v += gridDim.x) {
    int2 rec = ofl[v];
    int imv = rec.x & 0x3FFF, h = rec.x >> 14;
    float wv = __int_as_float(rec.y);
    atomicAdd(&out[(size_t)c * NHT + h], wv * xT[((size_t)imv << 7) + c]);
  }
}

extern "C" void kernel_launch(void* const* d_in, const int* in_sizes, int n_in,
                              void* d_out, int out_size, void* d_ws, size_t ws_size,
                              hipStream_t stream) {
  const float* input_im = (const float*)d_in[0];
  const int*   im_idx   = (const int*)d_in[1];
  const int*   ht_idx   = (const int*)d_in[2];
  const float* weight   = (const float*)d_in[3];
  float*       out      = (float*)d_out;
  const int N = in_sizes[1];

  // workspace layout (~26.5 MB)
  char* w = (char*)d_ws;
  float* xT      = (float*)(w + 0);           //  8,388,608 B (HW*BC f32)
  int2*  bkt     = (int2*) (w + 8388608);     // 18,087,936 B (NB*CAPB int2)
  int*   gcur    = (int*)  (w + 26476544);    //      2,208 B (NB i32, padded)
  int*   ofl_cnt = (int*)  (w + 26480640);    //        128 B
  int2*  ofl     = (int2*) (w + 26480768);    //     65,536 B

  k_zero<<<(NB + 256) / 256, 256, 0, stream>>>(gcur, ofl_cnt);
  k_transpose_in<<<dim3(HW / 32, BC / 32), dim3(32, 8), 0, stream>>>(input_im, xT);
  k_bucket<<<(N + VPB - 1) / VPB, 256, 0, stream>>>(im_idx, ht_idx, weight, N,
                                                    gcur, bkt, ofl_cnt, ofl);
  k_accum2<<<NB, 256, 0, stream>>>(bkt, gcur, xT, out);
  k_overflow<<<16, BC, 0, stream>>>(ofl_cnt, ofl, xT, out);
}

// Round 5
// 249.870 us; speedup vs baseline: 5.8213x; 5.8213x over previous
//
#include <hip/hip_runtime.h>

// IM2HT Hough voting:
//   out[b,c,ht] = sum_{n: ht_idx[n]==ht} input_im[b,c,im_idx[n]] * weight[n]
// B*C = 128, HW = 16384, NHT = 184*180 = 33120, N = 1.5M votes.
//
// Pipeline:
//   1. k_zero         : zero bucket cursors + overflow counter
//   2. k_transpose_in : in[BC][HW] -> xT0[HW][64], xT1[HW][64]  (4 MB halves)
//   3. k_bucket       : multi-split votes into 552 coarse ht-ranges (60 bins each)
//   4. k_resort       : per-range LDS counting sort -> fine-bin-contiguous records
//                       + foffs/fcnt per fine bin
//   5. k_accum3 (x2)  : one wave per fine bin, lane = channel, unroll-4;
//                       pass p gathers only xTp (4 MB = one XCD L2) -> L2-resident
//   6. k_transpose_out: outT[NHT][128] -> out[128][NHT]
//   7. k_overflow     : exact-correctness fallback (empty in practice)

#define HW   16384
#define BC   128
#define NHT  33120
#define RB   60            // ht bins per coarse range
#define NB   552           // NHT / RB
#define CAPB 3584          // record capacity per range (mean 2717, +16 sigma)
#define VPB  4096          // votes per k_bucket block
#define OFL_CAP 8192

typedef int iv4 __attribute__((ext_vector_type(4)));

__global__ void k_zero(int* __restrict__ gcur, int* __restrict__ ofl_cnt) {
  int i = blockIdx.x * blockDim.x + threadIdx.x;
  if (i < NB) gcur[i] = 0;
  if (i == NB) *ofl_cnt = 0;
}

// in [BC][HW] -> xT0 [HW][64] (ch 0..63), xT1 [HW][64] (ch 64..127)
__global__ void k_transpose_in(const float* __restrict__ in,
                               float* __restrict__ xT0, float* __restrict__ xT1) {
  __shared__ float tile[32][33];
  int hw0 = blockIdx.x * 32, bc0 = blockIdx.y * 32;
  int tx = threadIdx.x, ty = threadIdx.y;
#pragma unroll
  for (int k = 0; k < 32; k += 8)
    tile[ty + k][tx] = in[(size_t)(bc0 + ty + k) * HW + hw0 + tx];  // coalesced on hw
  __syncthreads();
  float* xTp = (bc0 < 64) ? xT0 : xT1;
  int c0 = bc0 & 63;
#pragma unroll
  for (int k = 0; k < 32; k += 8)
    xTp[(size_t)(hw0 + ty + k) * 64 + c0 + tx] = tile[tx][ty + k];  // coalesced on c
}

__global__ __launch_bounds__(256) void k_bucket(
    const int* __restrict__ im, const int* __restrict__ ht,
    const float* __restrict__ wt, int n,
    int* __restrict__ gcur, int2* __restrict__ bkt,
    int* __restrict__ ofl_cnt, int2* __restrict__ ofl) {
  __shared__ int cnt[NB];
  __shared__ int base[NB];
  int tid = threadIdx.x;
  int i0 = blockIdx.x * VPB;
  for (int b = tid; b < NB; b += 256) cnt[b] = 0;
  __syncthreads();
  int hv[16];
#pragma unroll
  for (int k = 0; k < 16; ++k) {
    int i = i0 + k * 256 + tid;
    hv[k] = (i < n) ? ht[i] : -1;
    if (i < n) atomicAdd(&cnt[hv[k] / RB], 1);
  }
  __syncthreads();
  for (int b = tid; b < NB; b += 256) {
    int c = cnt[b];
    base[b] = c ? atomicAdd(&gcur[b], c) : 0;  // reserve private chunk
    cnt[b] = 0;                                 // reuse as local cursor
  }
  __syncthreads();
#pragma unroll
  for (int k = 0; k < 16; ++k) {
    int i = i0 + k * 256 + tid;
    if (i < n) {
      int h = hv[k];
      int b = h / RB;
      int hl = h - b * RB;
      int pos = base[b] + atomicAdd(&cnt[b], 1);
      if (pos < CAPB) {
        bkt[(size_t)b * CAPB + pos] =
            make_int2((im[i] & 0x3FFF) | (hl << 14), __float_as_int(wt[i]));
      } else {
        int o = atomicAdd(ofl_cnt, 1);
        if (o < OFL_CAP)
          ofl[o] = make_int2((im[i] & 0x3FFF) | (h << 14), __float_as_int(wt[i]));
      }
    }
  }
}

// per-range LDS counting sort into fine-bin-contiguous order
__global__ __launch_bounds__(256) void k_resort(
    const int2* __restrict__ bkt, const int* __restrict__ gcur,
    int2* __restrict__ fsorted, int* __restrict__ foffs, int* __restrict__ fcnt) {
  __shared__ int hist[RB];
  __shared__ int off[RB];
  int r = blockIdx.x, tid = threadIdx.x;
  if (tid < RB) hist[tid] = 0;
  __syncthreads();
  int n = gcur[r];
  if (n > CAPB) n = CAPB;
  const int2* s = bkt + (size_t)r * CAPB;
  for (int i = tid; i < n; i += 256)
    atomicAdd(&hist[s[i].x >> 14], 1);
  __syncthreads();
  if (tid == 0) {
    int run = 0;
    for (int b = 0; b < RB; ++b) { off[b] = run; run += hist[b]; }
  }
  __syncthreads();
  if (tid < RB) {
    foffs[r * RB + tid] = r * CAPB + off[tid];
    fcnt[r * RB + tid] = hist[tid];
    hist[tid] = 0;  // reuse as cursor
  }
  __syncthreads();
  for (int i = tid; i < n; i += 256) {
    int2 v = s[i];
    int hl = v.x >> 14;
    int pos = off[hl] + atomicAdd(&hist[hl], 1);
    fsorted[(size_t)r * CAPB + pos] = make_int2(v.x & 0x3FFF, v.y);
  }
}

// one wave per fine bin; lane = channel within half p; xTp is 4 MB -> L2-resident
__global__ __launch_bounds__(256) void k_accum3(
    const int2* __restrict__ fsorted, const int* __restrict__ foffs,
    const int* __restrict__ fcnt, const float* __restrict__ xTp,
    float* __restrict__ outT, int p) {
  int bin = (int)((blockIdx.x * blockDim.x + threadIdx.x) >> 6);
  int lane = threadIdx.x & 63;
  if (bin >= NHT) return;
  int start = foffs[bin], n = fcnt[bin];
  const int* s = (const int*)(fsorted + start);
  float a0 = 0.f, a1 = 0.f, a2 = 0.f, a3 = 0.f;
  int i = 0;
  for (; i + 4 <= n; i += 4) {
    iv4 v01 = __builtin_nontemporal_load((const iv4*)(s + 2 * i));
    iv4 v23 = __builtin_nontemporal_load((const iv4*)(s + 2 * i + 4));
    float x0 = xTp[((size_t)v01.x << 6) + lane];
    float x1 = xTp[((size_t)v01.z << 6) + lane];
    float x2 = xTp[((size_t)v23.x << 6) + lane];
    float x3 = xTp[((size_t)v23.z << 6) + lane];
    a0 = fmaf(__int_as_float(v01.y), x0, a0);
    a1 = fmaf(__int_as_float(v01.w), x1, a1);
    a2 = fmaf(__int_as_float(v23.y), x2, a2);
    a3 = fmaf(__int_as_float(v23.w), x3, a3);
  }
  for (; i < n; ++i) {
    int vx = s[2 * i], vy = s[2 * i + 1];
    a0 = fmaf(__int_as_float(vy), xTp[((size_t)vx << 6) + lane], a0);
  }
  float r = (a0 + a1) + (a2 + a3);
  __builtin_nontemporal_store(r, outT + ((size_t)bin << 7) + (p << 6) + lane);
}

// outT [NHT][BC] -> out [BC][NHT]   (NHT = 1035*32, BC = 4*32)
__global__ void k_transpose_out(const float* __restrict__ outT, float* __restrict__ out) {
  __shared__ float tile[32][33];
  int ht0 = blockIdx.x * 32, bc0 = blockIdx.y * 32;
  int tx = threadIdx.x, ty = threadIdx.y;
#pragma unroll
  for (int k = 0; k < 32; k += 8)
    tile[ty + k][tx] = outT[(size_t)(ht0 + ty + k) * BC + bc0 + tx];  // coalesced on bc
  __syncthreads();
#pragma unroll
  for (int k = 0; k < 32; k += 8)
    out[(size_t)(bc0 + ty + k) * NHT + ht0 + tx] = tile[tx][ty + k];  // coalesced on ht
}

// exact-correctness fallback; *ofl_cnt == 0 in practice -> immediate exit
__global__ void k_overflow(const int* __restrict__ ofl_cnt, const int2* __restrict__ ofl,
                           const float* __restrict__ xT0, const float* __restrict__ xT1,
                           float* __restrict__ out) {
  int cnt = *ofl_cnt;
  if (cnt > OFL_CAP) cnt = OFL_CAP;
  int c = threadIdx.x;  // 0..127 channel
  const float* xTp = (c < 64) ? xT0 : xT1;
  int cl = c & 63;
  for (int v = blockIdx.x; v < cnt; v += gridDim.x) {
    int2 rec = ofl[v];
    int imv = rec.x & 0x3FFF, h = rec.x >> 14;
    float wv = __int_as_float(rec.y);
    atomicAdd(&out[(size_t)c * NHT + h], wv * xTp[((size_t)imv << 6) + cl]);
  }
}

extern "C" void kernel_launch(void* const* d_in, const int* in_sizes, int n_in,
                              void* d_out, int out_size, void* d_ws, size_t ws_size,
                              hipStream_t stream) {
  const float* input_im = (const float*)d_in[0];
  const int*   im_idx   = (const int*)d_in[1];
  const int*   ht_idx   = (const int*)d_in[2];
  const float* weight   = (const float*)d_in[3];
  float*       out      = (float*)d_out;
  const int N = in_sizes[1];

  // workspace layout (~57.5 MB)
  char* w = (char*)d_ws;
  float* xT0     = (float*)(w + 0);           //  4,194,304 B (HW*64 f32)
  float* xT1     = (float*)(w + 4194304);     //  4,194,304 B
  int2*  bkt     = (int2*) (w + 8388608);     // 15,826,944 B (NB*CAPB int2)
  int2*  fsorted = (int2*) (w + 24215552);    // 15,826,944 B
  float* outT    = (float*)(w + 40042496);    // 16,957,440 B (NHT*BC f32)
  int*   foffs   = (int*)  (w + 56999936);    //    132,480 B (NHT i32)
  int*   fcnt    = (int*)  (w + 57132416);    //    132,480 B
  int*   gcur    = (int*)  (w + 57264896);    //      2,304 B (NB, padded)
  int*   ofl_cnt = (int*)  (w + 57267200);    //        128 B
  int2*  ofl     = (int2*) (w + 57267328);    //     65,536 B

  k_zero<<<(NB + 256) / 256, 256, 0, stream>>>(gcur, ofl_cnt);
  k_transpose_in<<<dim3(HW / 32, BC / 32), dim3(32, 8), 0, stream>>>(input_im, xT0, xT1);
  k_bucket<<<(N + VPB - 1) / VPB, 256, 0, stream>>>(im_idx, ht_idx, weight, N,
                                                    gcur, bkt, ofl_cnt, ofl);
  k_resort<<<NB, 256, 0, stream>>>(bkt, gcur, fsorted, foffs, fcnt);
  k_accum3<<<(NHT * 64 + 255) / 256, 256, 0, stream>>>(fsorted, foffs, fcnt, xT0, outT, 0);
  k_accum3<<<(NHT * 64 + 255) / 256, 256, 0, stream>>>(fsorted, foffs, fcnt, xT1, outT, 1);
  k_transpose_out<<<dim3(NHT / 32, BC / 32), dim3(32, 8), 0, stream>>>(outT, out);
  k_overflow<<<16, BC, 0, stream>>>(ofl_cnt, ofl, xT0, xT1, out);
}

// Round 6
// 196.012 us; speedup vs baseline: 7.4208x; 1.2748x over previous
//
#include <hip/hip_runtime.h>

// IM2HT Hough voting:
//   out[b,c,ht] = sum_{n: ht_idx[n]==ht} input_im[b,c,im_idx[n]] * weight[n]
// B*C = 128, HW = 16384, NHT = 184*180 = 33120, N = 1.5M votes.
//
// Pipeline:
//   1. k_zero         : zero bucket cursors + overflow counter
//   2. k_transpose_in : in[BC][HW] -> xT[HW][128] (512 B per pixel row)
//   3. k_bucket       : multi-split votes into 552 coarse ht-ranges (60 bins each)
//   4. k_resort       : per-range LDS counting sort -> fine-bin-contiguous records,
//                       each bin PADDED to even count with a weight-0 dummy
//   5. k_accum4       : one wave per fine bin; half-wave = vote parity, lane owns
//                       4 channels -> one float4 gather serves 2 votes (4x fewer
//                       vmem instrs than R5); shfl_xor(32) reduce; 512 B store
//   6. k_transpose_out: outT[NHT][128] -> out[128][NHT]
//   7. k_overflow     : exact-correctness fallback (empty in practice)

#define HW   16384
#define BC   128
#define NHT  33120
#define RB   60            // ht bins per coarse range
#define NB   552           // NHT / RB
#define CAPB 3680          // slots per range incl. padding (mean 2717)
#define CAPR 3620          // raw record clamp (leaves 60 pad slots), +17 sigma
#define VPB  4096          // votes per k_bucket block
#define OFL_CAP 8192

typedef int iv4 __attribute__((ext_vector_type(4)));

__global__ void k_zero(int* __restrict__ gcur, int* __restrict__ ofl_cnt) {
  int i = blockIdx.x * blockDim.x + threadIdx.x;
  if (i < NB) gcur[i] = 0;
  if (i == NB) *ofl_cnt = 0;
}

// in [BC][HW] -> xT [HW][BC]
__global__ void k_transpose_in(const float* __restrict__ in, float* __restrict__ xT) {
  __shared__ float tile[32][33];
  int hw0 = blockIdx.x * 32, bc0 = blockIdx.y * 32;
  int tx = threadIdx.x, ty = threadIdx.y;
#pragma unroll
  for (int k = 0; k < 32; k += 8)
    tile[ty + k][tx] = in[(size_t)(bc0 + ty + k) * HW + hw0 + tx];  // coalesced on hw
  __syncthreads();
#pragma unroll
  for (int k = 0; k < 32; k += 8)
    xT[(size_t)(hw0 + ty + k) * BC + bc0 + tx] = tile[tx][ty + k];  // coalesced on bc
}

__global__ __launch_bounds__(256) void k_bucket(
    const int* __restrict__ im, const int* __restrict__ ht,
    const float* __restrict__ wt, int n,
    int* __restrict__ gcur, int2* __restrict__ bkt,
    int* __restrict__ ofl_cnt, int2* __restrict__ ofl) {
  __shared__ int cnt[NB];
  __shared__ int base[NB];
  int tid = threadIdx.x;
  int i0 = blockIdx.x * VPB;
  for (int b = tid; b < NB; b += 256) cnt[b] = 0;
  __syncthreads();
  int hv[16];
#pragma unroll
  for (int k = 0; k < 16; ++k) {
    int i = i0 + k * 256 + tid;
    hv[k] = (i < n) ? ht[i] : -1;
    if (i < n) atomicAdd(&cnt[hv[k] / RB], 1);
  }
  __syncthreads();
  for (int b = tid; b < NB; b += 256) {
    int c = cnt[b];
    base[b] = c ? atomicAdd(&gcur[b], c) : 0;  // reserve private chunk
    cnt[b] = 0;                                 // reuse as local cursor
  }
  __syncthreads();
#pragma unroll
  for (int k = 0; k < 16; ++k) {
    int i = i0 + k * 256 + tid;
    if (i < n) {
      int h = hv[k];
      int b = h / RB;
      int hl = h - b * RB;
      int pos = base[b] + atomicAdd(&cnt[b], 1);
      if (pos < CAPR) {
        bkt[(size_t)b * CAPB + pos] =
            make_int2((im[i] & 0x3FFF) | (hl << 14), __float_as_int(wt[i]));
      } else {
        int o = atomicAdd(ofl_cnt, 1);
        if (o < OFL_CAP)
          ofl[o] = make_int2((im[i] & 0x3FFF) | (h << 14), __float_as_int(wt[i]));
      }
    }
  }
}

// per-range LDS counting sort into fine-bin-contiguous order, bins padded to even
__global__ __launch_bounds__(256) void k_resort(
    const int2* __restrict__ bkt, const int* __restrict__ gcur,
    int2* __restrict__ fsorted, int* __restrict__ foffs, int* __restrict__ fcnt) {
  __shared__ int hist[RB];
  __shared__ int off[RB];
  int r = blockIdx.x, tid = threadIdx.x;
  if (tid < RB) hist[tid] = 0;
  __syncthreads();
  int n = gcur[r];
  if (n > CAPR) n = CAPR;
  const int2* s = bkt + (size_t)r * CAPB;
  for (int i = tid; i < n; i += 256)
    atomicAdd(&hist[s[i].x >> 14], 1);
  __syncthreads();
  if (tid == 0) {
    int run = 0;
    for (int b = 0; b < RB; ++b) { off[b] = run; run += (hist[b] + 1) & ~1; }
  }
  __syncthreads();
  if (tid < RB) {
    foffs[r * RB + tid] = r * CAPB + off[tid];
    fcnt[r * RB + tid] = (hist[tid] + 1) & ~1;   // padded even count
    if (hist[tid] & 1)                           // weight-0 dummy in pad slot
      fsorted[(size_t)r * CAPB + off[tid] + hist[tid]] = make_int2(0, 0);
    hist[tid] = 0;  // reuse as cursor
  }
  __syncthreads();
  for (int i = tid; i < n; i += 256) {
    int2 v = s[i];
    int hl = v.x >> 14;
    int pos = off[hl] + atomicAdd(&hist[hl], 1);
    fsorted[(size_t)r * CAPB + pos] = make_int2(v.x & 0x3FFF, v.y);
  }
}

// one wave per fine bin; half-wave = vote parity, lane owns channels 4*cl..4*cl+3
__global__ __launch_bounds__(256) void k_accum4(
    const int2* __restrict__ fsorted, const int* __restrict__ foffs,
    const int* __restrict__ fcnt, const float* __restrict__ xT,
    float* __restrict__ outT) {
  int gid = blockIdx.x * blockDim.x + threadIdx.x;
  int bin = __builtin_amdgcn_readfirstlane(gid >> 6);  // wave-uniform -> SGPR
  if (bin >= NHT) return;
  int lane = threadIdx.x & 63;
  int half = lane >> 5;    // 0: even votes, 1: odd votes
  int cl = lane & 31;      // channel group
  int start = foffs[bin], n = fcnt[bin];  // n even (padded)
  const int* s = (const int*)(fsorted + start);
  const float* xb = xT + (cl << 2);
  float4 a0 = {0,0,0,0}, a1 = {0,0,0,0}, a2 = {0,0,0,0}, a3 = {0,0,0,0};
  int i = 0;
  for (; i + 8 <= n; i += 8) {  // 8 votes: 4 uniform record loads + 4 float4 gathers
    iv4 q0 = *(const iv4*)(s + 2 * i);
    iv4 q1 = *(const iv4*)(s + 2 * i + 4);
    iv4 q2 = *(const iv4*)(s + 2 * i + 8);
    iv4 q3 = *(const iv4*)(s + 2 * i + 12);
    int im0 = half ? q0.z : q0.x;  float w0 = __int_as_float(half ? q0.w : q0.y);
    int im1 = half ? q1.z : q1.x;  float w1 = __int_as_float(half ? q1.w : q1.y);
    int im2 = half ? q2.z : q2.x;  float w2 = __int_as_float(half ? q2.w : q2.y);
    int im3 = half ? q3.z : q3.x;  float w3 = __int_as_float(half ? q3.w : q3.y);
    float4 x0 = *(const float4*)(xb + ((size_t)im0 << 7));
    float4 x1 = *(const float4*)(xb + ((size_t)im1 << 7));
    float4 x2 = *(const float4*)(xb + ((size_t)im2 << 7));
    float4 x3 = *(const float4*)(xb + ((size_t)im3 << 7));
    a0.x = fmaf(w0, x0.x, a0.x); a0.y = fmaf(w0, x0.y, a0.y);
    a0.z = fmaf(w0, x0.z, a0.z); a0.w = fmaf(w0, x0.w, a0.w);
    a1.x = fmaf(w1, x1.x, a1.x); a1.y = fmaf(w1, x1.y, a1.y);
    a1.z = fmaf(w1, x1.z, a1.z); a1.w = fmaf(w1, x1.w, a1.w);
    a2.x = fmaf(w2, x2.x, a2.x); a2.y = fmaf(w2, x2.y, a2.y);
    a2.z = fmaf(w2, x2.z, a2.z); a2.w = fmaf(w2, x2.w, a2.w);
    a3.x = fmaf(w3, x3.x, a3.x); a3.y = fmaf(w3, x3.y, a3.y);
    a3.z = fmaf(w3, x3.z, a3.z); a3.w = fmaf(w3, x3.w, a3.w);
  }
  for (; i < n; i += 2) {
    iv4 q = *(const iv4*)(s + 2 * i);
    int imv = half ? q.z : q.x;  float wv = __int_as_float(half ? q.w : q.y);
    float4 x = *(const float4*)(xb + ((size_t)imv << 7));
    a0.x = fmaf(wv, x.x, a0.x); a0.y = fmaf(wv, x.y, a0.y);
    a0.z = fmaf(wv, x.z, a0.z); a0.w = fmaf(wv, x.w, a0.w);
  }
  float4 a;
  a.x = (a0.x + a1.x) + (a2.x + a3.x);
  a.y = (a0.y + a1.y) + (a2.y + a3.y);
  a.z = (a0.z + a1.z) + (a2.z + a3.z);
  a.w = (a0.w + a1.w) + (a2.w + a3.w);
  float4 r;
  r.x = a.x + __shfl_xor(a.x, 32);
  r.y = a.y + __shfl_xor(a.y, 32);
  r.z = a.z + __shfl_xor(a.z, 32);
  r.w = a.w + __shfl_xor(a.w, 32);
  if (lane < 32)
    ((float4*)(outT + ((size_t)bin << 7)))[lane] = r;  // 512 B coalesced
}

// outT [NHT][BC] -> out [BC][NHT]   (NHT = 1035*32, BC = 4*32)
__global__ void k_transpose_out(const float* __restrict__ outT, float* __restrict__ out) {
  __shared__ float tile[32][33];
  int ht0 = blockIdx.x * 32, bc0 = blockIdx.y * 32;
  int tx = threadIdx.x, ty = threadIdx.y;
#pragma unroll
  for (int k = 0; k < 32; k += 8)
    tile[ty + k][tx] = outT[(size_t)(ht0 + ty + k) * BC + bc0 + tx];  // coalesced on bc
  __syncthreads();
#pragma unroll
  for (int k = 0; k < 32; k += 8)
    out[(size_t)(bc0 + ty + k) * NHT + ht0 + tx] = tile[tx][ty + k];  // coalesced on ht
}

// exact-correctness fallback; *ofl_cnt == 0 in practice -> immediate exit
__global__ void k_overflow(const int* __restrict__ ofl_cnt, const int2* __restrict__ ofl,
                           const float* __restrict__ xT, float* __restrict__ out) {
  int cnt = *ofl_cnt;
  if (cnt > OFL_CAP) cnt = OFL_CAP;
  int c = threadIdx.x;  // 0..127 channel
  for (int v = blockIdx.x; v < cnt; v += gridDim.x) {
    int2 rec = ofl[v];
    int imv = rec.x & 0x3FFF, h = rec.x >> 14;
    float wv = __int_as_float(rec.y);
    atomicAdd(&out[(size_t)c * NHT + h], wv * xT[((size_t)imv << 7) + c]);
  }
}

extern "C" void kernel_launch(void* const* d_in, const int* in_sizes, int n_in,
                              void* d_out, int out_size, void* d_ws, size_t ws_size,
                              hipStream_t stream) {
  const float* input_im = (const float*)d_in[0];
  const int*   im_idx   = (const int*)d_in[1];
  const int*   ht_idx   = (const int*)d_in[2];
  const float* weight   = (const float*)d_in[3];
  float*       out      = (float*)d_out;
  const int N = in_sizes[1];

  // workspace layout (~58.2 MB)
  char* w = (char*)d_ws;
  float* xT      = (float*)(w + 0);           //  8,388,608 B (HW*BC f32)
  int2*  bkt     = (int2*) (w + 8388608);     // 16,250,880 B (NB*CAPB int2)
  int2*  fsorted = (int2*) (w + 24639488);    // 16,250,880 B
  float* outT    = (float*)(w + 40890368);    // 16,957,440 B (NHT*BC f32)
  int*   foffs   = (int*)  (w + 57847808);    //    132,480 B (NHT i32)
  int*   fcnt    = (int*)  (w + 57980288);    //    132,480 B
  int*   gcur    = (int*)  (w + 58112768);    //      2,304 B (NB, padded)
  int*   ofl_cnt = (int*)  (w + 58115072);    //        128 B
  int2*  ofl     = (int2*) (w + 58115200);    //     65,536 B

  k_zero<<<(NB + 256) / 256, 256, 0, stream>>>(gcur, ofl_cnt);
  k_transpose_in<<<dim3(HW / 32, BC / 32), dim3(32, 8), 0, stream>>>(input_im, xT);
  k_bucket<<<(N + VPB - 1) / VPB, 256, 0, stream>>>(im_idx, ht_idx, weight, N,
                                                    gcur, bkt, ofl_cnt, ofl);
  k_resort<<<NB, 256, 0, stream>>>(bkt, gcur, fsorted, foffs, fcnt);
  k_accum4<<<NHT * 64 / 256, 256, 0, stream>>>(fsorted, foffs, fcnt, xT, outT);
  k_transpose_out<<<dim3(NHT / 32, BC / 32), dim3(32, 8), 0, stream>>>(outT, out);
  k_overflow<<<16, BC, 0, stream>>>(ofl_cnt, ofl, xT, out);
}

// Round 7
// 159.307 us; speedup vs baseline: 9.1306x; 1.2304x over previous
//
#include <hip/hip_runtime.h>

// IM2HT Hough voting:
//   out[b,c,ht] = sum_{n: ht_idx[n]==ht} input_im[b,c,im_idx[n]] * weight[n]
// B*C = 128, HW = 16384, NHT = 184*180 = 33120, N = 1.5M votes.
//
// Pipeline:
//   1. k_zero         : zero bucket cursors + overflow counter
//   2. k_transpose_in : in[BC][HW] -> xTh[HW][128] bf16 (256 B/row, 4 MB = one XCD L2)
//   3. k_bucket       : multi-split votes into 552 coarse ht-ranges (60 bins each)
//   4. k_resort       : per-range LDS-staged counting sort -> fine-bin-contiguous
//                       records, bins padded to multiple of 4 (weight-0 dummies)
//   5. k_accum5       : one wave per fine bin; lane=(vote quarter, channel octet);
//                       one 16B bf16 gather serves 8 ch -> 1 gather instr per 4 votes,
//                       all L2-hits; shfl_xor(16,32) reduce; 512 B store
//   6. k_transpose_out: outT[NHT][128] -> out[128][NHT]
//   7. k_overflow     : exact-correctness fallback (empty in practice)

#define HW   16384
#define BC   128
#define NHT  33120
#define RB   60            // ht bins per coarse range
#define NB   552           // NHT / RB
#define CAPB 3712          // slots per range incl. padding (mean 2717)
#define CAPR 3528          // raw record clamp (184 pad slots), +15 sigma
#define VPB  4096          // votes per k_bucket block
#define OFL_CAP 8192

typedef int iv4 __attribute__((ext_vector_type(4)));

__device__ __forceinline__ unsigned short f2bf(float f) {
  unsigned int u = __float_as_uint(f);
  u = (u + 0x7fff + ((u >> 16) & 1)) >> 16;   // round-to-nearest-even
  return (unsigned short)u;
}

__global__ void k_zero(int* __restrict__ gcur, int* __restrict__ ofl_cnt) {
  int i = blockIdx.x * blockDim.x + threadIdx.x;
  if (i < NB) gcur[i] = 0;
  if (i == NB) *ofl_cnt = 0;
}

// in [BC][HW] f32 -> xTh [HW][BC] bf16
__global__ void k_transpose_in(const float* __restrict__ in,
                               unsigned short* __restrict__ xTh) {
  __shared__ float tile[32][33];
  int hw0 = blockIdx.x * 32, bc0 = blockIdx.y * 32;
  int tx = threadIdx.x, ty = threadIdx.y;
#pragma unroll
  for (int k = 0; k < 32; k += 8)
    tile[ty + k][tx] = in[(size_t)(bc0 + ty + k) * HW + hw0 + tx];  // coalesced on hw
  __syncthreads();
#pragma unroll
  for (int k = 0; k < 32; k += 8)
    xTh[(size_t)(hw0 + ty + k) * BC + bc0 + tx] = f2bf(tile[tx][ty + k]);
}

__global__ __launch_bounds__(256) void k_bucket(
    const int* __restrict__ im, const int* __restrict__ ht,
    const float* __restrict__ wt, int n,
    int* __restrict__ gcur, int2* __restrict__ bkt,
    int* __restrict__ ofl_cnt, int2* __restrict__ ofl) {
  __shared__ int cnt[NB];
  __shared__ int base[NB];
  int tid = threadIdx.x;
  int i0 = blockIdx.x * VPB;
  for (int b = tid; b < NB; b += 256) cnt[b] = 0;
  __syncthreads();
  int hv[16];
#pragma unroll
  for (int k = 0; k < 16; ++k) {
    int i = i0 + k * 256 + tid;
    hv[k] = (i < n) ? ht[i] : -1;
    if (i < n) atomicAdd(&cnt[hv[k] / RB], 1);
  }
  __syncthreads();
  for (int b = tid; b < NB; b += 256) {
    int c = cnt[b];
    base[b] = c ? atomicAdd(&gcur[b], c) : 0;  // reserve private chunk
    cnt[b] = 0;                                 // reuse as local cursor
  }
  __syncthreads();
#pragma unroll
  for (int k = 0; k < 16; ++k) {
    int i = i0 + k * 256 + tid;
    if (i < n) {
      int h = hv[k];
      int b = h / RB;
      int hl = h - b * RB;
      int pos = base[b] + atomicAdd(&cnt[b], 1);
      if (pos < CAPR) {
        bkt[(size_t)b * CAPB + pos] =
            make_int2((im[i] & 0x3FFF) | (hl << 14), __float_as_int(wt[i]));
      } else {
        int o = atomicAdd(ofl_cnt, 1);
        if (o < OFL_CAP)
          ofl[o] = make_int2((im[i] & 0x3FFF) | (h << 14), __float_as_int(wt[i]));
      }
    }
  }
}

// per-range LDS-staged counting sort; bins padded to multiple of 4
__global__ __launch_bounds__(256) void k_resort(
    const int2* __restrict__ bkt, const int* __restrict__ gcur,
    int2* __restrict__ fsorted, int* __restrict__ foffs, int* __restrict__ fcnt) {
  __shared__ int2 buf[CAPB];     // 29.7 KB staged records
  __shared__ int hist[RB];
  __shared__ int off[RB];
  int r = blockIdx.x, tid = threadIdx.x;
  int n = gcur[r];
  if (n > CAPR) n = CAPR;
  const int2* s = bkt + (size_t)r * CAPB;
  for (int i = tid; i < n; i += 256) buf[i] = s[i];   // single global read
  if (tid < RB) hist[tid] = 0;
  __syncthreads();
  for (int i = tid; i < n; i += 256)
    atomicAdd(&hist[buf[i].x >> 14], 1);
  __syncthreads();
  if (tid == 0) {
    int run = 0;
    for (int b = 0; b < RB; ++b) { off[b] = run; run += (hist[b] + 3) & ~3; }
  }
  __syncthreads();
  if (tid < RB) {
    int padded = (hist[tid] + 3) & ~3;
    foffs[r * RB + tid] = r * CAPB + off[tid];
    fcnt[r * RB + tid] = padded;
    for (int d = hist[tid]; d < padded; ++d)        // weight-0 dummies
      fsorted[(size_t)r * CAPB + off[tid] + d] = make_int2(0, 0);
    hist[tid] = 0;  // reuse as cursor
  }
  __syncthreads();
  for (int i = tid; i < n; i += 256) {
    int2 v = buf[i];
    int hl = v.x >> 14;
    int pos = off[hl] + atomicAdd(&hist[hl], 1);
    fsorted[(size_t)r * CAPB + pos] = make_int2(v.x & 0x3FFF, v.y);
  }
}

// select vote q's (im, w) from 4 packed records
__device__ __forceinline__ void pick4(iv4 a, iv4 b, int q, int& im, float& w) {
  int imx = (q & 2) ? b.x : a.x;
  int imz = (q & 2) ? b.z : a.z;
  im = (q & 1) ? imz : imx;
  int wx = (q & 2) ? b.y : a.y;
  int wz = (q & 2) ? b.w : a.w;
  w = __int_as_float((q & 1) ? wz : wx);
}

// one wave per fine bin; lane = (vote quarter q, channel octet cg)
__global__ __launch_bounds__(256) void k_accum5(
    const int2* __restrict__ fsorted, const int* __restrict__ foffs,
    const int* __restrict__ fcnt, const unsigned short* __restrict__ xTh,
    float* __restrict__ outT) {
  int gid = blockIdx.x * blockDim.x + threadIdx.x;
  int bin = __builtin_amdgcn_readfirstlane(gid >> 6);
  if (bin >= NHT) return;
  int lane = threadIdx.x & 63;
  int q = lane >> 4;       // vote quarter 0..3
  int cg = lane & 15;      // channel octet: channels 8*cg .. 8*cg+7
  int start = foffs[bin], n = fcnt[bin];  // n % 4 == 0
  const int* s = (const int*)(fsorted + start);
  const unsigned short* xb = xTh + (cg << 3);
  float acc[8] = {0, 0, 0, 0, 0, 0, 0, 0};

#define GATHER_FMA(IM, W)                                                     \
  {                                                                           \
    iv4 xd = *(const iv4*)(xb + ((size_t)(IM) << 7));                         \
    _Pragma("unroll") for (int c = 0; c < 4; ++c) {                           \
      float lo = __uint_as_float(((unsigned int)xd[c]) << 16);                \
      float hi = __uint_as_float(((unsigned int)xd[c]) & 0xffff0000u);        \
      acc[2 * c]     = fmaf((W), lo, acc[2 * c]);                             \
      acc[2 * c + 1] = fmaf((W), hi, acc[2 * c + 1]);                         \
    }                                                                         \
  }

  int i = 0;
  for (; i + 8 <= n; i += 8) {  // 8 votes: 4 uniform iv4 loads + 2 bf16x8 gathers
    iv4 r0 = __builtin_nontemporal_load((const iv4*)(s + 2 * i));
    iv4 r1 = __builtin_nontemporal_load((const iv4*)(s + 2 * i + 4));
    iv4 r2 = __builtin_nontemporal_load((const iv4*)(s + 2 * i + 8));
    iv4 r3 = __builtin_nontemporal_load((const iv4*)(s + 2 * i + 12));
    int im0; float w0; pick4(r0, r1, q, im0, w0);
    int im1; float w1; pick4(r2, r3, q, im1, w1);
    GATHER_FMA(im0, w0);
    GATHER_FMA(im1, w1);
  }
  for (; i < n; i += 4) {       // tail: one group of 4
    iv4 r0 = __builtin_nontemporal_load((const iv4*)(s + 2 * i));
    iv4 r1 = __builtin_nontemporal_load((const iv4*)(s + 2 * i + 4));
    int im0; float w0; pick4(r0, r1, q, im0, w0);
    GATHER_FMA(im0, w0);
  }
#undef GATHER_FMA

  // reduce across the 4 vote-quarters (lanes cg, cg+16, cg+32, cg+48)
  float r[8];
#pragma unroll
  for (int k = 0; k < 8; ++k) {
    float t = acc[k] + __shfl_xor(acc[k], 16);
    r[k] = t + __shfl_xor(t, 32);
  }
  if (lane < 16) {
    float4 lo = {r[0], r[1], r[2], r[3]};
    float4 hi = {r[4], r[5], r[6], r[7]};
    float4* dst = (float4*)(outT + ((size_t)bin << 7) + (cg << 3));
    __builtin_nontemporal_store(lo.x, &((float*)dst)[0]);
    __builtin_nontemporal_store(lo.y, &((float*)dst)[1]);
    __builtin_nontemporal_store(lo.z, &((float*)dst)[2]);
    __builtin_nontemporal_store(lo.w, &((float*)dst)[3]);
    __builtin_nontemporal_store(hi.x, &((float*)dst)[4]);
    __builtin_nontemporal_store(hi.y, &((float*)dst)[5]);
    __builtin_nontemporal_store(hi.z, &((float*)dst)[6]);
    __builtin_nontemporal_store(hi.w, &((float*)dst)[7]);
  }
}

// outT [NHT][BC] -> out [BC][NHT]   (NHT = 1035*32, BC = 4*32)
__global__ void k_transpose_out(const float* __restrict__ outT, float* __restrict__ out) {
  __shared__ float tile[32][33];
  int ht0 = blockIdx.x * 32, bc0 = blockIdx.y * 32;
  int tx = threadIdx.x, ty = threadIdx.y;
#pragma unroll
  for (int k = 0; k < 32; k += 8)
    tile[ty + k][tx] = outT[(size_t)(ht0 + ty + k) * BC + bc0 + tx];  // coalesced on bc
  __syncthreads();
#pragma unroll
  for (int k = 0; k < 32; k += 8)
    out[(size_t)(bc0 + ty + k) * NHT + ht0 + tx] = tile[tx][ty + k];  // coalesced on ht
}

// exact-correctness fallback; *ofl_cnt == 0 in practice -> immediate exit
__global__ void k_overflow(const int* __restrict__ ofl_cnt, const int2* __restrict__ ofl,
                           const unsigned short* __restrict__ xTh,
                           float* __restrict__ out) {
  int cnt = *ofl_cnt;
  if (cnt > OFL_CAP) cnt = OFL_CAP;
  int c = threadIdx.x;  // 0..127 channel
  for (int v = blockIdx.x; v < cnt; v += gridDim.x) {
    int2 rec = ofl[v];
    int imv = rec.x & 0x3FFF, h = rec.x >> 14;
    float wv = __int_as_float(rec.y);
    float xv = __uint_as_float(((unsigned int)xTh[((size_t)imv << 7) + c]) << 16);
    atomicAdd(&out[(size_t)c * NHT + h], wv * xv);
  }
}

extern "C" void kernel_launch(void* const* d_in, const int* in_sizes, int n_in,
                              void* d_out, int out_size, void* d_ws, size_t ws_size,
                              hipStream_t stream) {
  const float* input_im = (const float*)d_in[0];
  const int*   im_idx   = (const int*)d_in[1];
  const int*   ht_idx   = (const int*)d_in[2];
  const float* weight   = (const float*)d_in[3];
  float*       out      = (float*)d_out;
  const int N = in_sizes[1];

  // workspace layout (~54.3 MB)
  char* w = (char*)d_ws;
  unsigned short* xTh = (unsigned short*)(w + 0);  //  4,194,304 B (HW*BC bf16)
  int2*  bkt     = (int2*) (w + 4194304);     // 16,392,192 B (NB*CAPB int2)
  int2*  fsorted = (int2*) (w + 20586496);    // 16,392,192 B
  float* outT    = (float*)(w + 36978688);    // 16,957,440 B (NHT*BC f32)
  int*   foffs   = (int*)  (w + 53936128);    //    132,480 B (NHT i32)
  int*   fcnt    = (int*)  (w + 54068608);    //    132,480 B
  int*   gcur    = (int*)  (w + 54201088);    //      2,304 B (NB, padded)
  int*   ofl_cnt = (int*)  (w + 54203392);    //        128 B
  int2*  ofl     = (int2*) (w + 54203520);    //     65,536 B

  k_zero<<<(NB + 256) / 256, 256, 0, stream>>>(gcur, ofl_cnt);
  k_transpose_in<<<dim3(HW / 32, BC / 32), dim3(32, 8), 0, stream>>>(input_im, xTh);
  k_bucket<<<(N + VPB - 1) / VPB, 256, 0, stream>>>(im_idx, ht_idx, weight, N,
                                                    gcur, bkt, ofl_cnt, ofl);
  k_resort<<<NB, 256, 0, stream>>>(bkt, gcur, fsorted, foffs, fcnt);
  k_accum5<<<NHT * 64 / 256, 256, 0, stream>>>(fsorted, foffs, fcnt, xTh, outT);
  k_transpose_out<<<dim3(NHT / 32, BC / 32), dim3(32, 8), 0, stream>>>(outT, out);
  k_overflow<<<16, BC, 0, stream>>>(ofl_cnt, ofl, xTh, out);
}

// Round 8
// 152.892 us; speedup vs baseline: 9.5137x; 1.0420x over previous
//
#include <hip/hip_runtime.h>

// IM2HT Hough voting:
//   out[b,c,ht] = sum_{n: ht_idx[n]==ht} input_im[b,c,im_idx[n]] * weight[n]
// B*C = 128, HW = 16384, NHT = 184*180 = 33120, N = 1.5M votes.
//
// Pipeline:
//   1. k_zero         : zero bucket cursors + overflow counter
//   2. k_transpose_in : in[BC][HW] -> xTh[HW][128] bf16 (256 B/row, 4 MB = one XCD L2)
//   3. k_bucket       : multi-split votes into 552 coarse ht-ranges (60 bins each);
//                       1024 thr x 4 votes -> 16 waves/block hides atomic latency
//   4. k_resort       : per-range LDS-staged counting sort -> fine-bin-contiguous
//                       records, bins padded to multiple of 4 (weight-0 dummies)
//   5. k_accum5       : one wave per fine bin; lane=(vote quarter, channel octet);
//                       one 16B bf16 gather serves 8 ch -> 1 gather instr per 4 votes,
//                       all L2-hits; shfl_xor(16,32) reduce; 512 B store
//   6. k_transpose_out: outT[NHT][128] -> out[128][NHT]
//   7. k_overflow     : exact-correctness fallback (empty in practice)

#define HW   16384
#define BC   128
#define NHT  33120
#define RB   60            // ht bins per coarse range
#define NB   552           // NHT / RB
#define CAPB 3712          // slots per range incl. padding (mean 2717)
#define CAPR 3528          // raw record clamp (184 pad slots), +15 sigma
#define VPB  4096          // votes per k_bucket block
#define OFL_CAP 8192

typedef int iv4 __attribute__((ext_vector_type(4)));

__device__ __forceinline__ unsigned short f2bf(float f) {
  unsigned int u = __float_as_uint(f);
  u = (u + 0x7fff + ((u >> 16) & 1)) >> 16;   // round-to-nearest-even
  return (unsigned short)u;
}

__global__ void k_zero(int* __restrict__ gcur, int* __restrict__ ofl_cnt) {
  int i = blockIdx.x * blockDim.x + threadIdx.x;
  if (i < NB) gcur[i] = 0;
  if (i == NB) *ofl_cnt = 0;
}

// in [BC][HW] f32 -> xTh [HW][BC] bf16
__global__ void k_transpose_in(const float* __restrict__ in,
                               unsigned short* __restrict__ xTh) {
  __shared__ float tile[32][33];
  int hw0 = blockIdx.x * 32, bc0 = blockIdx.y * 32;
  int tx = threadIdx.x, ty = threadIdx.y;
#pragma unroll
  for (int k = 0; k < 32; k += 8)
    tile[ty + k][tx] = in[(size_t)(bc0 + ty + k) * HW + hw0 + tx];  // coalesced on hw
  __syncthreads();
#pragma unroll
  for (int k = 0; k < 32; k += 8)
    xTh[(size_t)(hw0 + ty + k) * BC + bc0 + tx] = f2bf(tile[tx][ty + k]);
}

// 1024 threads, 4 votes each (VPB = 4096 preserved -> same write-combining)
__global__ __launch_bounds__(1024) void k_bucket(
    const int* __restrict__ im, const int* __restrict__ ht,
    const float* __restrict__ wt, int n,
    int* __restrict__ gcur, int2* __restrict__ bkt,
    int* __restrict__ ofl_cnt, int2* __restrict__ ofl) {
  __shared__ int cnt[NB];
  __shared__ int base[NB];
  int tid = threadIdx.x;
  int i0 = blockIdx.x * VPB;
  for (int b = tid; b < NB; b += 1024) cnt[b] = 0;
  __syncthreads();
  int hv[4];
#pragma unroll
  for (int k = 0; k < 4; ++k) {
    int i = i0 + k * 1024 + tid;
    hv[k] = (i < n) ? ht[i] : -1;
    if (i < n) atomicAdd(&cnt[hv[k] / RB], 1);
  }
  __syncthreads();
  for (int b = tid; b < NB; b += 1024) {
    int c = cnt[b];
    base[b] = c ? atomicAdd(&gcur[b], c) : 0;  // reserve private chunk
    cnt[b] = 0;                                 // reuse as local cursor
  }
  __syncthreads();
#pragma unroll
  for (int k = 0; k < 4; ++k) {
    int i = i0 + k * 1024 + tid;
    if (i < n) {
      int h = hv[k];
      int b = h / RB;
      int hl = h - b * RB;
      int pos = base[b] + atomicAdd(&cnt[b], 1);
      if (pos < CAPR) {
        bkt[(size_t)b * CAPB + pos] =
            make_int2((im[i] & 0x3FFF) | (hl << 14), __float_as_int(wt[i]));
      } else {
        int o = atomicAdd(ofl_cnt, 1);
        if (o < OFL_CAP)
          ofl[o] = make_int2((im[i] & 0x3FFF) | (h << 14), __float_as_int(wt[i]));
      }
    }
  }
}

// per-range LDS-staged counting sort; bins padded to multiple of 4
__global__ __launch_bounds__(512) void k_resort(
    const int2* __restrict__ bkt, const int* __restrict__ gcur,
    int2* __restrict__ fsorted, int* __restrict__ foffs, int* __restrict__ fcnt) {
  __shared__ int2 buf[CAPB];     // 29.7 KB staged records
  __shared__ int hist[RB];
  __shared__ int off[RB];
  int r = blockIdx.x, tid = threadIdx.x;
  int n = gcur[r];
  if (n > CAPR) n = CAPR;
  const int2* s = bkt + (size_t)r * CAPB;
  for (int i = tid; i < n; i += 512) buf[i] = s[i];   // single global read
  if (tid < RB) hist[tid] = 0;
  __syncthreads();
  for (int i = tid; i < n; i += 512)
    atomicAdd(&hist[buf[i].x >> 14], 1);
  __syncthreads();
  if (tid == 0) {
    int run = 0;
    for (int b = 0; b < RB; ++b) { off[b] = run; run += (hist[b] + 3) & ~3; }
  }
  __syncthreads();
  if (tid < RB) {
    int padded = (hist[tid] + 3) & ~3;
    foffs[r * RB + tid] = r * CAPB + off[tid];
    fcnt[r * RB + tid] = padded;
    for (int d = hist[tid]; d < padded; ++d)        // weight-0 dummies
      fsorted[(size_t)r * CAPB + off[tid] + d] = make_int2(0, 0);
    hist[tid] = 0;  // reuse as cursor
  }
  __syncthreads();
  for (int i = tid; i < n; i += 512) {
    int2 v = buf[i];
    int hl = v.x >> 14;
    int pos = off[hl] + atomicAdd(&hist[hl], 1);
    fsorted[(size_t)r * CAPB + pos] = make_int2(v.x & 0x3FFF, v.y);
  }
}

// select vote q's (im, w) from 4 packed records
__device__ __forceinline__ void pick4(iv4 a, iv4 b, int q, int& im, float& w) {
  int imx = (q & 2) ? b.x : a.x;
  int imz = (q & 2) ? b.z : a.z;
  im = (q & 1) ? imz : imx;
  int wx = (q & 2) ? b.y : a.y;
  int wz = (q & 2) ? b.w : a.w;
  w = __int_as_float((q & 1) ? wz : wx);
}

// one wave per fine bin; lane = (vote quarter q, channel octet cg)
__global__ __launch_bounds__(256) void k_accum5(
    const int2* __restrict__ fsorted, const int* __restrict__ foffs,
    const int* __restrict__ fcnt, const unsigned short* __restrict__ xTh,
    float* __restrict__ outT) {
  int gid = blockIdx.x * blockDim.x + threadIdx.x;
  int bin = __builtin_amdgcn_readfirstlane(gid >> 6);
  if (bin >= NHT) return;
  int lane = threadIdx.x & 63;
  int q = lane >> 4;       // vote quarter 0..3
  int cg = lane & 15;      // channel octet: channels 8*cg .. 8*cg+7
  int start = foffs[bin], n = fcnt[bin];  // n % 4 == 0
  const int* s = (const int*)(fsorted + start);
  const unsigned short* xb = xTh + (cg << 3);
  float acc[8] = {0, 0, 0, 0, 0, 0, 0, 0};

#define GATHER_FMA(IM, W)                                                     \
  {                                                                           \
    iv4 xd = *(const iv4*)(xb + ((size_t)(IM) << 7));                         \
    _Pragma("unroll") for (int c = 0; c < 4; ++c) {                           \
      float lo = __uint_as_float(((unsigned int)xd[c]) << 16);                \
      float hi = __uint_as_float(((unsigned int)xd[c]) & 0xffff0000u);        \
      acc[2 * c]     = fmaf((W), lo, acc[2 * c]);                             \
      acc[2 * c + 1] = fmaf((W), hi, acc[2 * c + 1]);                         \
    }                                                                         \
  }

  int i = 0;
  for (; i + 8 <= n; i += 8) {  // 8 votes: 4 uniform iv4 loads + 2 bf16x8 gathers
    iv4 r0 = __builtin_nontemporal_load((const iv4*)(s + 2 * i));
    iv4 r1 = __builtin_nontemporal_load((const iv4*)(s + 2 * i + 4));
    iv4 r2 = __builtin_nontemporal_load((const iv4*)(s + 2 * i + 8));
    iv4 r3 = __builtin_nontemporal_load((const iv4*)(s + 2 * i + 12));
    int im0; float w0; pick4(r0, r1, q, im0, w0);
    int im1; float w1; pick4(r2, r3, q, im1, w1);
    GATHER_FMA(im0, w0);
    GATHER_FMA(im1, w1);
  }
  for (; i < n; i += 4) {       // tail: one group of 4
    iv4 r0 = __builtin_nontemporal_load((const iv4*)(s + 2 * i));
    iv4 r1 = __builtin_nontemporal_load((const iv4*)(s + 2 * i + 4));
    int im0; float w0; pick4(r0, r1, q, im0, w0);
    GATHER_FMA(im0, w0);
  }
#undef GATHER_FMA

  // reduce across the 4 vote-quarters (lanes cg, cg+16, cg+32, cg+48)
  float r[8];
#pragma unroll
  for (int k = 0; k < 8; ++k) {
    float t = acc[k] + __shfl_xor(acc[k], 16);
    r[k] = t + __shfl_xor(t, 32);
  }
  if (lane < 16) {
    float4 lo = {r[0], r[1], r[2], r[3]};
    float4 hi = {r[4], r[5], r[6], r[7]};
    float4* dst = (float4*)(outT + ((size_t)bin << 7) + (cg << 3));
    __builtin_nontemporal_store(lo.x, &((float*)dst)[0]);
    __builtin_nontemporal_store(lo.y, &((float*)dst)[1]);
    __builtin_nontemporal_store(lo.z, &((float*)dst)[2]);
    __builtin_nontemporal_store(lo.w, &((float*)dst)[3]);
    __builtin_nontemporal_store(hi.x, &((float*)dst)[4]);
    __builtin_nontemporal_store(hi.y, &((float*)dst)[5]);
    __builtin_nontemporal_store(hi.z, &((float*)dst)[6]);
    __builtin_nontemporal_store(hi.w, &((float*)dst)[7]);
  }
}

// outT [NHT][BC] -> out [BC][NHT]   (NHT = 1035*32, BC = 4*32)
__global__ void k_transpose_out(const float* __restrict__ outT, float* __restrict__ out) {
  __shared__ float tile[32][33];
  int ht0 = blockIdx.x * 32, bc0 = blockIdx.y * 32;
  int tx = threadIdx.x, ty = threadIdx.y;
#pragma unroll
  for (int k = 0; k < 32; k += 8)
    tile[ty + k][tx] = outT[(size_t)(ht0 + ty + k) * BC + bc0 + tx];  // coalesced on bc
  __syncthreads();
#pragma unroll
  for (int k = 0; k < 32; k += 8)
    out[(size_t)(bc0 + ty + k) * NHT + ht0 + tx] = tile[tx][ty + k];  // coalesced on ht
}

// exact-correctness fallback; *ofl_cnt == 0 in practice -> immediate exit
__global__ void k_overflow(const int* __restrict__ ofl_cnt, const int2* __restrict__ ofl,
                           const unsigned short* __restrict__ xTh,
                           float* __restrict__ out) {
  int cnt = *ofl_cnt;
  if (cnt > OFL_CAP) cnt = OFL_CAP;
  int c = threadIdx.x;  // 0..127 channel
  for (int v = blockIdx.x; v < cnt; v += gridDim.x) {
    int2 rec = ofl[v];
    int imv = rec.x & 0x3FFF, h = rec.x >> 14;
    float wv = __int_as_float(rec.y);
    float xv = __uint_as_float(((unsigned int)xTh[((size_t)imv << 7) + c]) << 16);
    atomicAdd(&out[(size_t)c * NHT + h], wv * xv);
  }
}

extern "C" void kernel_launch(void* const* d_in, const int* in_sizes, int n_in,
                              void* d_out, int out_size, void* d_ws, size_t ws_size,
                              hipStream_t stream) {
  const float* input_im = (const float*)d_in[0];
  const int*   im_idx   = (const int*)d_in[1];
  const int*   ht_idx   = (const int*)d_in[2];
  const float* weight   = (const float*)d_in[3];
  float*       out      = (float*)d_out;
  const int N = in_sizes[1];

  // workspace layout (~54.3 MB)
  char* w = (char*)d_ws;
  unsigned short* xTh = (unsigned short*)(w + 0);  //  4,194,304 B (HW*BC bf16)
  int2*  bkt     = (int2*) (w + 4194304);     // 16,392,192 B (NB*CAPB int2)
  int2*  fsorted = (int2*) (w + 20586496);    // 16,392,192 B
  float* outT    = (float*)(w + 36978688);    // 16,957,440 B (NHT*BC f32)
  int*   foffs   = (int*)  (w + 53936128);    //    132,480 B (NHT i32)
  int*   fcnt    = (int*)  (w + 54068608);    //    132,480 B
  int*   gcur    = (int*)  (w + 54201088);    //      2,304 B (NB, padded)
  int*   ofl_cnt = (int*)  (w + 54203392);    //        128 B
  int2*  ofl     = (int2*) (w + 54203520);    //     65,536 B

  k_zero<<<(NB + 256) / 256, 256, 0, stream>>>(gcur, ofl_cnt);
  k_transpose_in<<<dim3(HW / 32, BC / 32), dim3(32, 8), 0, stream>>>(input_im, xTh);
  k_bucket<<<(N + VPB - 1) / VPB, 1024, 0, stream>>>(im_idx, ht_idx, weight, N,
                                                     gcur, bkt, ofl_cnt, ofl);
  k_resort<<<NB, 512, 0, stream>>>(bkt, gcur, fsorted, foffs, fcnt);
  k_accum5<<<NHT * 64 / 256, 256, 0, stream>>>(fsorted, foffs, fcnt, xTh, outT);
  k_transpose_out<<<dim3(NHT / 32, BC / 32), dim3(32, 8), 0, stream>>>(outT, out);
  k_overflow<<<16, BC, 0, stream>>>(ofl_cnt, ofl, xTh, out);
}